// Round 2
// baseline (3350.079 us; speedup 1.0000x reference)
//
#include <hip/hip_runtime.h>
#include <hip/hip_bf16.h>
#include <math.h>

// ---------------------------------------------------------------------------
// TransformerKBrnnDecoder forward, fp32 baseline v2 (128x128x16 tile).
//
// Shapes: B=128, T=256, H=512, KB_DIMS=3, K_HOPS=2, KB_TOTAL=32768.
// Outputs (concat in d_out): u_t_k (128*32768) | updated_hidden (128*256*512)
//                            | updated_cell (128*256*512).
//
// Workspace layout (floats), total ~203.1 MB:
//   qW   [6*128*512]   u [6*4096]   engv [32768]
//   buf0 [32768*512] (aliases Ebuf=3*4096*512)   buf1 [32768*512]
//   arnb [32768*512]
// ---------------------------------------------------------------------------

#define BM 128
#define BN 128
#define BK 16
#define APAD 4

// EPI: 0=relu  1=sigmoid  2=tanh  3=none
//      4=tanh(acc+b)*aux1 (new_info, in-place ok)
//      5=final: s=sigmoid(acc+b); uc=aux2+aux1*eng[row]; C=uc; out2=s*tanh(uc)
//      6=tanh(acc + aux1[(row>>5)*N+col])  (e = tanh(kbWk + qW), no bias)
template<int EPI>
__global__ __launch_bounds__(256)
void gemm_k(const float* __restrict__ A1, const float* __restrict__ A2,
            int kSplit, long long aStrideZ,
            const float* __restrict__ Bmat, long long bStrideZ,
            const float* __restrict__ bias,
            float* __restrict__ C, long long cStrideZ,
            int M, int N, int K,
            const float* __restrict__ aux1, long long aux1StrideZ,
            const float* __restrict__ aux2,
            const float* __restrict__ engv,
            float* __restrict__ out2)
{
    __shared__ float As[BK][BM + APAD];
    __shared__ float Bs[BK][BN];

    const int z = blockIdx.z;
    const float* A1z  = A1 + (size_t)z * aStrideZ;
    const float* Bz   = Bmat + (size_t)z * bStrideZ;
    float*       Cz   = C + (size_t)z * cStrideZ;
    const float* aux1z = aux1 ? (aux1 + (size_t)z * aux1StrideZ) : nullptr;

    const int m0 = blockIdx.y * BM;
    const int n0 = blockIdx.x * BN;
    const int tid = threadIdx.x;
    const int tm = tid >> 4;          // 0..15 -> rows tm*4 (+64)
    const int tn = tid & 15;          // 0..15 -> cols tn*4 (+64)
    const int lar = tid >> 2;         // 0..63  A-load rows lar, lar+64
    const int lac = (tid & 3) << 2;   // 0,4,8,12 A-load k (float4)
    const int lbr = tid >> 5;         // 0..7   B-load k rows lbr, lbr+8
    const int lbc = (tid & 31) << 2;  // 0..124 B-load col (float4)

    float acc[2][2][4][4] = {};

    for (int k0 = 0; k0 < K; k0 += BK) {
        const float* Ap; int kk; int lda;
        if (k0 < kSplit) { Ap = A1z; kk = k0;          lda = kSplit;     }
        else             { Ap = A2;  kk = k0 - kSplit; lda = K - kSplit; }

        float4 av0 = *(const float4*)(Ap + (size_t)(m0 + lar)      * lda + (kk + lac));
        float4 av1 = *(const float4*)(Ap + (size_t)(m0 + lar + 64) * lda + (kk + lac));
        As[lac + 0][lar]      = av0.x;
        As[lac + 1][lar]      = av0.y;
        As[lac + 2][lar]      = av0.z;
        As[lac + 3][lar]      = av0.w;
        As[lac + 0][lar + 64] = av1.x;
        As[lac + 1][lar + 64] = av1.y;
        As[lac + 2][lar + 64] = av1.z;
        As[lac + 3][lar + 64] = av1.w;

        float4 bv0 = *(const float4*)(Bz + (size_t)(k0 + lbr)     * N + (n0 + lbc));
        float4 bv1 = *(const float4*)(Bz + (size_t)(k0 + lbr + 8) * N + (n0 + lbc));
        *(float4*)&Bs[lbr][lbc]     = bv0;
        *(float4*)&Bs[lbr + 8][lbc] = bv1;

        __syncthreads();
#pragma unroll
        for (int k = 0; k < BK; ++k) {
            float4 a0 = *(const float4*)&As[k][tm << 2];
            float4 a1 = *(const float4*)&As[k][(tm << 2) + 64];
            float4 b0 = *(const float4*)&Bs[k][tn << 2];
            float4 b1 = *(const float4*)&Bs[k][(tn << 2) + 64];
            float a[2][4] = {{a0.x, a0.y, a0.z, a0.w}, {a1.x, a1.y, a1.z, a1.w}};
            float b[2][4] = {{b0.x, b0.y, b0.z, b0.w}, {b1.x, b1.y, b1.z, b1.w}};
#pragma unroll
            for (int ib = 0; ib < 2; ++ib)
#pragma unroll
            for (int i = 0; i < 4; ++i)
#pragma unroll
            for (int jb = 0; jb < 2; ++jb)
#pragma unroll
            for (int j = 0; j < 4; ++j)
                acc[ib][jb][i][j] = fmaf(a[ib][i], b[jb][j], acc[ib][jb][i][j]);
        }
        __syncthreads();
    }

#pragma unroll
    for (int ib = 0; ib < 2; ++ib)
#pragma unroll
    for (int i = 0; i < 4; ++i) {
        const int row = m0 + ib * 64 + (tm << 2) + i;
#pragma unroll
        for (int jb = 0; jb < 2; ++jb)
#pragma unroll
        for (int j = 0; j < 4; ++j) {
            const int col = n0 + jb * 64 + (tn << 2) + j;
            float v = acc[ib][jb][i][j];
            if (bias) v += bias[col];
            const size_t off = (size_t)row * N + col;
            if constexpr (EPI == 0) {
                Cz[off] = v > 0.f ? v : 0.f;
            } else if constexpr (EPI == 1) {
                Cz[off] = 1.f / (1.f + expf(-v));
            } else if constexpr (EPI == 2) {
                Cz[off] = tanhf(v);
            } else if constexpr (EPI == 3) {
                Cz[off] = v;
            } else if constexpr (EPI == 4) {
                Cz[off] = tanhf(v) * aux1z[off];
            } else if constexpr (EPI == 5) {
                float s  = 1.f / (1.f + expf(-v));
                float cv = aux2[off];
                float uc = cv + aux1z[off] * engv[row];
                Cz[off]   = uc;            // updated_cell
                out2[off] = s * tanhf(uc); // updated_hidden
            } else if constexpr (EPI == 6) {
                Cz[off] = tanhf(v + aux1z[(size_t)(row >> 5) * N + col]);
            }
        }
    }
}

// u[idx][row] = sum_n E[z][row][n] * v_att[idx][n],  idx = hopBase + z
__global__ __launch_bounds__(256)
void reduce_u_k(const float* __restrict__ E, const float* __restrict__ v_att,
                float* __restrict__ u, int hopBase)
{
    const int row = blockIdx.x;           // 0..4095 (= b*32 + j)
    const int z   = blockIdx.y;           // 0..2
    const int idx = hopBase + z;
    const float* e = E + ((size_t)z * 4096 + row) * 512;
    const float* v = v_att + (size_t)idx * 512;
    const int t = threadIdx.x;
    float s = e[t] * v[t] + e[t + 256] * v[t + 256];
#pragma unroll
    for (int off = 32; off > 0; off >>= 1) s += __shfl_down(s, off, 64);
    __shared__ float wsum[4];
    if ((t & 63) == 0) wsum[t >> 6] = s;
    __syncthreads();
    if (t == 0) u[(size_t)idx * 4096 + row] = wsum[0] + wsum[1] + wsum[2] + wsum[3];
}

// u_t_k[b][k] = mask ? 0 : sum of 6 broadcast-indexed u terms
__global__ __launch_bounds__(256)
void utk_k(const float* __restrict__ u, const int* __restrict__ mask,
           float* __restrict__ out)
{
    const int b = blockIdx.y;
    __shared__ float su[6][32];
    const int t = threadIdx.x;
    if (t < 192) su[t >> 5][t & 31] = u[(size_t)(t >> 5) * 4096 + b * 32 + (t & 31)];
    __syncthreads();
    const int base = blockIdx.x * 2048;
#pragma unroll
    for (int d = 0; d < 8; ++d) {
        const int k = base + d * 256 + t;
        float v = su[0][k >> 10] + su[1][(k >> 5) & 31] + su[2][k & 31]
                + su[3][k >> 10] + su[4][(k >> 5) & 31] + su[5][k & 31];
        const size_t off = (size_t)b * 32768 + k;
        if (mask[off]) v = 0.f;
        out[off] = v;
    }
}

// engv[row] = dot(cell[row,:], eng_w)
__global__ __launch_bounds__(256)
void eng_k(const float* __restrict__ cell, const float* __restrict__ ew,
           float* __restrict__ engv)
{
    const int row  = blockIdx.x * 4 + (threadIdx.x >> 6);
    const int lane = threadIdx.x & 63;
    const float* c = cell + (size_t)row * 512;
    float s = 0.f;
#pragma unroll
    for (int w = 0; w < 8; ++w) s = fmaf(c[w * 64 + lane], ew[w * 64 + lane], s);
#pragma unroll
    for (int off = 32; off > 0; off >>= 1) s += __shfl_down(s, off, 64);
    if (lane == 0) engv[row] = s;
}

extern "C" void kernel_launch(void* const* d_in, const int* in_sizes, int n_in,
                              void* d_out, int out_size, void* d_ws, size_t ws_size,
                              hipStream_t stream)
{
    const float* query   = (const float*)d_in[0];
    const float* kb_keys = (const float*)d_in[1];
    const float* Wq      = (const float*)d_in[2];
    const float* Wk      = (const float*)d_in[3];
    const float* v_att   = (const float*)d_in[4];
    const float* x       = (const float*)d_in[5];
    const float* hidden  = (const float*)d_in[6];
    const float* cell    = (const float*)d_in[7];
    const float* arn_w1  = (const float*)d_in[8];
    const float* arn_b1  = (const float*)d_in[9];
    const float* arn_w2  = (const float*)d_in[10];
    const float* arn_b2  = (const float*)d_in[11];
    const float* arn_w3  = (const float*)d_in[12];
    const float* arn_b3  = (const float*)d_in[13];
    const float* add_w1  = (const float*)d_in[14];
    const float* add_b1  = (const float*)d_in[15];
    const float* add_w2  = (const float*)d_in[16];
    const float* add_b2  = (const float*)d_in[17];
    const float* add_w3  = (const float*)d_in[18];
    const float* add_b3  = (const float*)d_in[19];
    const float* eng_w   = (const float*)d_in[20];
    const float* wc_w1   = (const float*)d_in[21];
    const float* wc_b1   = (const float*)d_in[22];
    const float* wc_w2   = (const float*)d_in[23];
    const float* wc_b2   = (const float*)d_in[24];
    const float* wc_w3   = (const float*)d_in[25];
    const float* wc_b3   = (const float*)d_in[26];
    const float* wc_w4   = (const float*)d_in[27];
    const float* wc_b4   = (const float*)d_in[28];
    const int*   kb_mask = (const int*)d_in[29];   // jax bool -> int32 per harness

    float* ws   = (float*)d_ws;
    float* qW   = ws;                    // 6*128*512      = 393216
    float* u    = qW + 393216;           // 6*4096         = 24576
    float* engv = u + 24576;             // 32768
    float* buf0 = engv + 32768;          // 32768*512 (aliases Ebuf)
    float* buf1 = buf0 + 16777216;
    float* arnb = buf1 + 16777216;
    float* Ebuf = buf0;

    float* out_utk  = (float*)d_out;                 // 4194304
    float* out_hid  = out_utk + 4194304;             // 16777216
    float* out_cell = out_hid + 16777216;            // 16777216

    const dim3 blk(256);

    // ---- Part 1: KB attention -> u_t_k ----
    // qW[idx] = query @ Wq[idx]   (M=128, N=512, K=512, batched z=6)
    gemm_k<3><<<dim3(4, 1, 6), blk, 0, stream>>>(
        query, nullptr, 512, 0, Wq, 262144, nullptr, qW, 65536,
        128, 512, 512, nullptr, 0, nullptr, nullptr, nullptr);

    for (int hop = 0; hop < 2; ++hop) {
        // E[z] = tanh(kb_keys[z] @ Wk[hop*3+z] + qW[hop*3+z])  (M=4096, z=3)
        gemm_k<6><<<dim3(4, 32, 3), blk, 0, stream>>>(
            kb_keys, nullptr, 512, 2097152,
            Wk + (size_t)hop * 3 * 262144, 262144, nullptr,
            Ebuf, 2097152, 4096, 512, 512,
            qW + (size_t)hop * 3 * 65536, 65536, nullptr, nullptr, nullptr);
        reduce_u_k<<<dim3(4096, 3), blk, 0, stream>>>(Ebuf, v_att, u, hop * 3);
    }
    utk_k<<<dim3(16, 128), blk, 0, stream>>>(u, kb_mask, out_utk);

    // ---- Part 2: RNN cell MLPs ----  (M = B*T = 32768)
    const int M = 32768;
    const dim3 g(4, 256, 1);
    // arn chain
    gemm_k<0><<<g, blk, 0, stream>>>(x, hidden, 512, 0, arn_w1, 0, arn_b1, buf0, 0,
                                     M, 512, 1024, nullptr, 0, nullptr, nullptr, nullptr);
    gemm_k<0><<<g, blk, 0, stream>>>(buf0, nullptr, 512, 0, arn_w2, 0, arn_b2, buf1, 0,
                                     M, 512, 512, nullptr, 0, nullptr, nullptr, nullptr);
    gemm_k<1><<<g, blk, 0, stream>>>(buf1, nullptr, 512, 0, arn_w3, 0, arn_b3, arnb, 0,
                                     M, 512, 512, nullptr, 0, nullptr, nullptr, nullptr);
    // add chain; final epilogue multiplies by arn -> new_info (in-place into arnb)
    gemm_k<0><<<g, blk, 0, stream>>>(x, hidden, 512, 0, add_w1, 0, add_b1, buf0, 0,
                                     M, 512, 1024, nullptr, 0, nullptr, nullptr, nullptr);
    gemm_k<0><<<g, blk, 0, stream>>>(buf0, nullptr, 512, 0, add_w2, 0, add_b2, buf1, 0,
                                     M, 512, 512, nullptr, 0, nullptr, nullptr, nullptr);
    gemm_k<4><<<g, blk, 0, stream>>>(buf1, nullptr, 512, 0, add_w3, 0, add_b3, arnb, 0,
                                     M, 512, 512, arnb, 0, nullptr, nullptr, nullptr);
    // wc chain
    gemm_k<0><<<g, blk, 0, stream>>>(x, hidden, 512, 0, wc_w1, 0, wc_b1, buf0, 0,
                                     M, 512, 1024, nullptr, 0, nullptr, nullptr, nullptr);
    gemm_k<0><<<g, blk, 0, stream>>>(buf0, nullptr, 512, 0, wc_w2, 0, wc_b2, buf1, 0,
                                     M, 512, 512, nullptr, 0, nullptr, nullptr, nullptr);
    gemm_k<0><<<g, blk, 0, stream>>>(buf1, nullptr, 512, 0, wc_w3, 0, wc_b3, buf0, 0,
                                     M, 512, 512, nullptr, 0, nullptr, nullptr, nullptr);
    // eng row-dots, then final fused epilogue writes updated_cell + updated_hidden
    eng_k<<<dim3(8192), blk, 0, stream>>>(cell, eng_w, engv);
    gemm_k<5><<<g, blk, 0, stream>>>(buf0, nullptr, 512, 0, wc_w4, 0, wc_b4, out_cell, 0,
                                     M, 512, 512, arnb, 0, cell, engv, out_hid);
}

// Round 3
// 1364.513 us; speedup vs baseline: 2.4551x; 2.4551x over previous
//
#include <hip/hip_runtime.h>
#include <math.h>
#include <stdint.h>

// ---------------------------------------------------------------------------
// TransformerKBrnnDecoder forward — bf16x2 split MFMA version.
// B=128, T=256, H=512. All GEMMs: D = A*B via 3 MFMAs (AhBh + AhBl + AlBh),
// fp32 accumulate. Weights pre-transposed+split into a pre-staged LDS-image
// pool (in the d_out scratch region before it's written). Activations are
// reg-staged fp32->bf16x2; intermediates stored packed (hi|lo<<16) ushort2.
//
// ws layout (floats): arnb[16.7M] (qW@0, u@393216 aliased, dead before arn3)
//   ping @16777216 (16.7M, aliases E fp32 in part 1)
//   pong @33554432 (16.7M; engv @pong base, wc4 planes @pong+32768, both
//   written after pong's last read by wc3)
// total = 50,331,648 floats = 201.3 MB (proven ws >= 203.1 MB).
// ---------------------------------------------------------------------------

typedef __attribute__((ext_vector_type(8))) short bf16x8v;
typedef __attribute__((ext_vector_type(4))) float f32x4;

__device__ __forceinline__ unsigned short f2bf(float x) {
    unsigned u = __float_as_uint(x);
    u += 0x7fff + ((u >> 16) & 1);          // RNE
    return (unsigned short)(u >> 16);
}
__device__ __forceinline__ float bf2f(unsigned short h) {
    return __uint_as_float(((unsigned)h) << 16);
}

// ---------------------------------------------------------------------------
// Weight conversion: W fp32 [K][512] -> pre-staged chunks per (nblk,kstep):
// 8192 ushorts = [plane2][cg8][c4][col16][j8], elem = split(W[k][n]),
// k = kstep*32 + c*8 + j, n = nblk*128 + cg*16 + col.
// ---------------------------------------------------------------------------
#define NCONV 22
struct ConvTab {
    const float* src[NCONV];
    unsigned dstOff[NCONV];   // ushort elems into pool
    int ksteps[NCONV];        // K/32
    int startBlk[NCONV];
    int nEntries;
};

__global__ __launch_bounds__(256)
void conv_w_k(ConvTab tab, unsigned short* __restrict__ pool)
{
    __shared__ float tile[32][136];
    const int blk = blockIdx.x;
    int e = 0;
    while (e + 1 < tab.nEntries && blk >= tab.startBlk[e + 1]) ++e;
    const int local = blk - tab.startBlk[e];
    const int ks = tab.ksteps[e];
    const int kstep = local % ks;
    const int nblk = local / ks;
    const float* W = tab.src[e];
    const int t = threadIdx.x;
    const int kr = t >> 3, cq = (t & 7) << 4;
    const float* srow = W + (size_t)(kstep * 32 + kr) * 512 + nblk * 128 + cq;
    *(float4*)&tile[kr][cq + 0]  = *(const float4*)(srow + 0);
    *(float4*)&tile[kr][cq + 4]  = *(const float4*)(srow + 4);
    *(float4*)&tile[kr][cq + 8]  = *(const float4*)(srow + 8);
    *(float4*)&tile[kr][cq + 12] = *(const float4*)(srow + 12);
    __syncthreads();
    unsigned short* dst = pool + tab.dstOff[e] + (size_t)(nblk * ks + kstep) * 8192 + t * 32;
#pragma unroll
    for (int g = 0; g < 4; ++g) {
        unsigned pk[4];
#pragma unroll
        for (int hw = 0; hw < 4; ++hw) {
            unsigned short vs[2];
#pragma unroll
            for (int s2 = 0; s2 < 2; ++s2) {
                int o = t * 32 + g * 8 + hw * 2 + s2;
                int plane = o >> 12, rem = o & 4095;
                int cg = rem >> 9, c = (rem >> 7) & 3, col = (rem >> 3) & 15, j = rem & 7;
                float val = tile[c * 8 + j][cg * 16 + col];
                unsigned short h = f2bf(val);
                vs[s2] = plane ? f2bf(val - bf2f(h)) : h;
            }
            pk[hw] = (unsigned)vs[0] | ((unsigned)vs[1] << 16);
        }
        uint4 v; v.x = pk[0]; v.y = pk[1]; v.z = pk[2]; v.w = pk[3];
        *(uint4*)(dst + g * 8) = v;
    }
}

// ---------------------------------------------------------------------------
// bf16x2 MFMA GEMM. 128x128 tile, 4 waves of 64x64, BK=32.
// EPI: 0=relu->packed bf16x2  1=sigmoid fp32  3=none fp32
//      4=tanh(acc+b)*aux1 fp32 (in-place ok)
//      5=final: s=sigmoid(acc+b); uc=aux2+aux1*engv[row]; C=uc; out2=s*tanh(uc)
//      6=tanh(acc + aux1[(row>>5)*N+col]) fp32
// AFMT: 0 = fp32 A (split in kernel; optional concat A1|A2 at kSplit)
//       1 = packed bf16x2 A (uint per elem)
// ---------------------------------------------------------------------------
template<int EPI, int AFMT>
__global__ __launch_bounds__(256, 2)
void mgemm_k(const void* __restrict__ A1v, const void* __restrict__ A2v,
             int kSplit, long long aStrideZ,
             const unsigned short* __restrict__ Bpool, long long bStrideZ,
             const float* __restrict__ bias,
             void* __restrict__ Cv, long long cStrideZ,
             int M, int N, int K,
             const float* __restrict__ aux1, long long aux1StrideZ,
             const float* __restrict__ aux2,
             const float* __restrict__ engv,
             float* __restrict__ out2)
{
    __shared__ __align__(16) unsigned short As[8192];   // [plane][rg8][c4][r16][j8]
    __shared__ __align__(16) unsigned short Bs[8192];   // [plane][cg8][c4][col16][j8]

    // XCD-bijective swizzle (contiguous row-panels per XCD)
    int wg = blockIdx.y * gridDim.x + blockIdx.x;
    const int nwg = gridDim.x * gridDim.y;
    if ((nwg & 7) == 0 && nwg >= 16) {
        int q = nwg >> 3;
        wg = (wg & 7) * q + (wg >> 3);
    }
    const int bx = wg % gridDim.x;
    const int by = wg / gridDim.x;

    const int z = blockIdx.z;
    const int m0 = by * 128, n0 = bx * 128;
    const int tid = threadIdx.x;
    const int lane = tid & 63;
    const int wid = tid >> 6;
    const int wm = wid >> 1, wn = wid & 1;

    const unsigned short* Bz = Bpool + (size_t)z * bStrideZ;
    const int ksteps = K >> 5;

    f32x4 acc[4][4];
#pragma unroll
    for (int i = 0; i < 4; ++i)
#pragma unroll
        for (int j = 0; j < 4; ++j) acc[i][j] = (f32x4){0.f, 0.f, 0.f, 0.f};

    const int r  = tid >> 1;           // staging row 0..127
    const int p  = (tid & 1) << 4;     // k-offset 0 / 16
    const int c0 = (tid & 1) << 1;     // chunk 0 / 2
    const int abase = (r >> 4) * 512 + (r & 15) * 8;
    const int laneOff = ((lane >> 4) << 7) + ((lane & 15) << 3);  // c*128+col*8

    for (int k0 = 0; k0 < K; k0 += 32) {
        // ---- stage B: linear 16KB copy of pre-staged chunk ----
        const unsigned short* chunk = Bz + (size_t)(bx * ksteps + (k0 >> 5)) * 8192;
#pragma unroll
        for (int qq = 0; qq < 4; ++qq) {
            uint4 v = *(const uint4*)(chunk + ((qq << 8) + tid) * 8);
            *(uint4*)&Bs[((qq << 8) + tid) * 8] = v;
        }
        // ---- stage A: 16 elems/thread -> hi/lo planes ----
        {
            unsigned ph[8], pl_[8];
            if (AFMT == 0) {
                const float* Ap; int kk, lda;
                if (k0 < kSplit) { Ap = (const float*)A1v + (size_t)z * aStrideZ; kk = k0; lda = kSplit; }
                else             { Ap = (const float*)A2v; kk = k0 - kSplit; lda = K - kSplit; }
                const float* srow = Ap + (size_t)(m0 + r) * lda + kk + p;
#pragma unroll
                for (int q4 = 0; q4 < 4; ++q4) {
                    float4 f = *(const float4*)(srow + q4 * 4);
                    float fv[4] = {f.x, f.y, f.z, f.w};
                    unsigned short h[4], l[4];
#pragma unroll
                    for (int e2 = 0; e2 < 4; ++e2) {
                        h[e2] = f2bf(fv[e2]);
                        l[e2] = f2bf(fv[e2] - bf2f(h[e2]));
                    }
                    ph[q4 * 2 + 0] = (unsigned)h[0] | ((unsigned)h[1] << 16);
                    ph[q4 * 2 + 1] = (unsigned)h[2] | ((unsigned)h[3] << 16);
                    pl_[q4 * 2 + 0] = (unsigned)l[0] | ((unsigned)l[1] << 16);
                    pl_[q4 * 2 + 1] = (unsigned)l[2] | ((unsigned)l[3] << 16);
                }
            } else {
                const unsigned* Ap = (const unsigned*)A1v + (size_t)z * aStrideZ;
                const unsigned* srow = Ap + (size_t)(m0 + r) * K + k0 + p;
#pragma unroll
                for (int q4 = 0; q4 < 4; ++q4) {
                    uint4 u4 = *(const uint4*)(srow + q4 * 4);
                    unsigned uv[4] = {u4.x, u4.y, u4.z, u4.w};
                    ph[q4 * 2 + 0] = (uv[0] & 0xffffu) | ((uv[1] & 0xffffu) << 16);
                    ph[q4 * 2 + 1] = (uv[2] & 0xffffu) | ((uv[3] & 0xffffu) << 16);
                    pl_[q4 * 2 + 0] = (uv[0] >> 16) | (uv[1] & 0xffff0000u);
                    pl_[q4 * 2 + 1] = (uv[2] >> 16) | (uv[3] & 0xffff0000u);
                }
            }
            uint4 vh0; vh0.x = ph[0]; vh0.y = ph[1]; vh0.z = ph[2]; vh0.w = ph[3];
            uint4 vh1; vh1.x = ph[4]; vh1.y = ph[5]; vh1.z = ph[6]; vh1.w = ph[7];
            uint4 vl0; vl0.x = pl_[0]; vl0.y = pl_[1]; vl0.z = pl_[2]; vl0.w = pl_[3];
            uint4 vl1; vl1.x = pl_[4]; vl1.y = pl_[5]; vl1.z = pl_[6]; vl1.w = pl_[7];
            *(uint4*)&As[abase + c0 * 128]              = vh0;
            *(uint4*)&As[abase + (c0 + 1) * 128]        = vh1;
            *(uint4*)&As[4096 + abase + c0 * 128]       = vl0;
            *(uint4*)&As[4096 + abase + (c0 + 1) * 128] = vl1;
        }
        __syncthreads();
        // ---- fragments + MFMA ----
        bf16x8v ah[2][4], bh[2][4];
#pragma unroll
        for (int mi = 0; mi < 4; ++mi) {
            ah[0][mi] = *(const bf16x8v*)&As[(wm * 4 + mi) * 512 + laneOff];
            ah[1][mi] = *(const bf16x8v*)&As[4096 + (wm * 4 + mi) * 512 + laneOff];
        }
#pragma unroll
        for (int ni = 0; ni < 4; ++ni) {
            bh[0][ni] = *(const bf16x8v*)&Bs[(wn * 4 + ni) * 512 + laneOff];
            bh[1][ni] = *(const bf16x8v*)&Bs[4096 + (wn * 4 + ni) * 512 + laneOff];
        }
#pragma unroll
        for (int mi = 0; mi < 4; ++mi)
#pragma unroll
            for (int ni = 0; ni < 4; ++ni) {
                acc[mi][ni] = __builtin_amdgcn_mfma_f32_16x16x32_bf16(ah[0][mi], bh[0][ni], acc[mi][ni], 0, 0, 0);
                acc[mi][ni] = __builtin_amdgcn_mfma_f32_16x16x32_bf16(ah[0][mi], bh[1][ni], acc[mi][ni], 0, 0, 0);
                acc[mi][ni] = __builtin_amdgcn_mfma_f32_16x16x32_bf16(ah[1][mi], bh[0][ni], acc[mi][ni], 0, 0, 0);
            }
        __syncthreads();
    }

    // ---- epilogue ----
    float* Cf = (float*)Cv + (size_t)z * cStrideZ;
    unsigned* Cu = (unsigned*)Cv + (size_t)z * cStrideZ;
    const float* aux1z = aux1 ? aux1 + (size_t)z * aux1StrideZ : nullptr;
    const int lr = (lane >> 4) << 2;
    const int lc = lane & 15;
#pragma unroll
    for (int mi = 0; mi < 4; ++mi)
#pragma unroll
        for (int ni = 0; ni < 4; ++ni) {
            const int col = n0 + wn * 64 + ni * 16 + lc;
            const float bv = bias ? bias[col] : 0.f;
#pragma unroll
            for (int rI = 0; rI < 4; ++rI) {
                const int row = m0 + wm * 64 + mi * 16 + lr + rI;
                float v = acc[mi][ni][rI] + bv;
                const size_t off = (size_t)row * N + col;
                if (EPI == 0) {
                    v = v > 0.f ? v : 0.f;
                    unsigned short h = f2bf(v);
                    unsigned short l = f2bf(v - bf2f(h));
                    Cu[off] = (unsigned)h | ((unsigned)l << 16);
                } else if (EPI == 1) {
                    Cf[off] = 1.f / (1.f + expf(-v));
                } else if (EPI == 3) {
                    Cf[off] = v;
                } else if (EPI == 4) {
                    Cf[off] = tanhf(v) * aux1z[off];
                } else if (EPI == 5) {
                    float s = 1.f / (1.f + expf(-v));
                    float uc = aux2[off] + aux1z[off] * engv[row];
                    Cf[off] = uc;
                    out2[off] = s * tanhf(uc);
                } else if (EPI == 6) {
                    Cf[off] = tanhf(v + aux1z[(size_t)(row >> 5) * N + col]);
                }
            }
        }
}

// u[idx][row] = sum_n E[z][row][n] * v_att[idx][n]
__global__ __launch_bounds__(256)
void reduce_u_k(const float* __restrict__ E, const float* __restrict__ v_att,
                float* __restrict__ u, int hopBase)
{
    const int row = blockIdx.x;
    const int z = blockIdx.y;
    const int idx = hopBase + z;
    const float* e = E + ((size_t)z * 4096 + row) * 512;
    const float* v = v_att + (size_t)idx * 512;
    const int t = threadIdx.x;
    float s = e[t] * v[t] + e[t + 256] * v[t + 256];
#pragma unroll
    for (int off = 32; off > 0; off >>= 1) s += __shfl_down(s, off, 64);
    __shared__ float wsum[4];
    if ((t & 63) == 0) wsum[t >> 6] = s;
    __syncthreads();
    if (t == 0) u[(size_t)idx * 4096 + row] = wsum[0] + wsum[1] + wsum[2] + wsum[3];
}

__global__ __launch_bounds__(256)
void utk_k(const float* __restrict__ u, const int* __restrict__ mask,
           float* __restrict__ out)
{
    const int b = blockIdx.y;
    __shared__ float su[6][32];
    const int t = threadIdx.x;
    if (t < 192) su[t >> 5][t & 31] = u[(size_t)(t >> 5) * 4096 + b * 32 + (t & 31)];
    __syncthreads();
    const int base = blockIdx.x * 2048;
#pragma unroll
    for (int d = 0; d < 8; ++d) {
        const int k = base + d * 256 + t;
        float v = su[0][k >> 10] + su[1][(k >> 5) & 31] + su[2][k & 31]
                + su[3][k >> 10] + su[4][(k >> 5) & 31] + su[5][k & 31];
        const size_t off = (size_t)b * 32768 + k;
        if (mask[off]) v = 0.f;
        out[off] = v;
    }
}

__global__ __launch_bounds__(256)
void eng_k(const float* __restrict__ cell, const float* __restrict__ ew,
           float* __restrict__ engv)
{
    const int row = blockIdx.x * 4 + (threadIdx.x >> 6);
    const int lane = threadIdx.x & 63;
    const float* c = cell + (size_t)row * 512;
    float s = 0.f;
#pragma unroll
    for (int w = 0; w < 8; ++w) s = fmaf(c[w * 64 + lane], ew[w * 64 + lane], s);
#pragma unroll
    for (int off = 32; off > 0; off >>= 1) s += __shfl_down(s, off, 64);
    if (lane == 0) engv[row] = s;
}

extern "C" void kernel_launch(void* const* d_in, const int* in_sizes, int n_in,
                              void* d_out, int out_size, void* d_ws, size_t ws_size,
                              hipStream_t stream)
{
    const float* query   = (const float*)d_in[0];
    const float* kb_keys = (const float*)d_in[1];
    const float* Wq      = (const float*)d_in[2];
    const float* Wk      = (const float*)d_in[3];
    const float* v_att   = (const float*)d_in[4];
    const float* x       = (const float*)d_in[5];
    const float* hidden  = (const float*)d_in[6];
    const float* cell    = (const float*)d_in[7];
    const float* arn_w1  = (const float*)d_in[8];
    const float* arn_b1  = (const float*)d_in[9];
    const float* arn_w2  = (const float*)d_in[10];
    const float* arn_b2  = (const float*)d_in[11];
    const float* arn_w3  = (const float*)d_in[12];
    const float* arn_b3  = (const float*)d_in[13];
    const float* add_w1  = (const float*)d_in[14];
    const float* add_b1  = (const float*)d_in[15];
    const float* add_w2  = (const float*)d_in[16];
    const float* add_b2  = (const float*)d_in[17];
    const float* add_w3  = (const float*)d_in[18];
    const float* add_b3  = (const float*)d_in[19];
    const float* eng_w   = (const float*)d_in[20];
    const float* wc_w1   = (const float*)d_in[21];
    const float* wc_b1   = (const float*)d_in[22];
    const float* wc_w2   = (const float*)d_in[23];
    const float* wc_b2   = (const float*)d_in[24];
    const float* wc_w3   = (const float*)d_in[25];
    const float* wc_b3   = (const float*)d_in[26];
    const float* wc_w4   = (const float*)d_in[27];
    const float* wc_b4   = (const float*)d_in[28];
    const int*   kb_mask = (const int*)d_in[29];

    float* ws = (float*)d_ws;
    float* qWf  = ws;                       // aliased in arnb (dead before arn3)
    float* u    = ws + 393216;              // aliased in arnb
    float* arnb = ws;                       // fp32 [32768*512]
    unsigned* ping = (unsigned*)(ws + 16777216);
    unsigned* pong = (unsigned*)(ws + 33554432);
    float* Ebuf = (float*)ping;             // part-1 alias
    float* engv = (float*)pong;             // written after pong's last read
    unsigned short* wc4pool = (unsigned short*)(ws + 33554432 + 32768);

    float* out_utk  = (float*)d_out;
    float* out_hid  = out_utk + 4194304;
    float* out_cell = out_hid + 16777216;
    unsigned short* pool0 = (unsigned short*)out_hid;   // weight pool, dead by final gemm... (all but wc_w4)

    // pool offsets (ushort elems)
    const unsigned WqO = 0, WkO = 3145728;
    const unsigned w1O[3]  = {6291456, 7340032, 8388608};          // arn, add, wc
    const unsigned w2O[6]  = {9437184, 9961472, 10485760, 11010048, 11534336, 12058624};
    // order: arn_w2, arn_w3, add_w2, add_w3, wc_w2, wc_w3

    // ---- early weight conversion (21 entries, 1536 blocks) ----
    ConvTab tE;
    int blkAcc = 0, ne = 0;
    for (int zz = 0; zz < 6; ++zz) { tE.src[ne] = Wq + (size_t)zz * 262144; tE.dstOff[ne] = WqO + zz * 524288; tE.ksteps[ne] = 16; tE.startBlk[ne] = blkAcc; blkAcc += 64; ++ne; }
    for (int zz = 0; zz < 6; ++zz) { tE.src[ne] = Wk + (size_t)zz * 262144; tE.dstOff[ne] = WkO + zz * 524288; tE.ksteps[ne] = 16; tE.startBlk[ne] = blkAcc; blkAcc += 64; ++ne; }
    const float* w1s[3] = {arn_w1, add_w1, wc_w1};
    for (int m = 0; m < 3; ++m) { tE.src[ne] = w1s[m]; tE.dstOff[ne] = w1O[m]; tE.ksteps[ne] = 32; tE.startBlk[ne] = blkAcc; blkAcc += 128; ++ne; }
    const float* w2s[6] = {arn_w2, arn_w3, add_w2, add_w3, wc_w2, wc_w3};
    for (int m = 0; m < 6; ++m) { tE.src[ne] = w2s[m]; tE.dstOff[ne] = w2O[m]; tE.ksteps[ne] = 16; tE.startBlk[ne] = blkAcc; blkAcc += 64; ++ne; }
    tE.nEntries = ne;
    conv_w_k<<<dim3(blkAcc), dim3(256), 0, stream>>>(tE, pool0);

    const dim3 blk(256);

    // ---- Part 1: KB attention ----
    mgemm_k<3, 0><<<dim3(4, 1, 6), blk, 0, stream>>>(
        query, nullptr, 512, 0, pool0 + WqO, 524288, nullptr,
        qWf, 65536, 128, 512, 512, nullptr, 0, nullptr, nullptr, nullptr);
    for (int hop = 0; hop < 2; ++hop) {
        mgemm_k<6, 0><<<dim3(4, 32, 3), blk, 0, stream>>>(
            kb_keys, nullptr, 512, 2097152,
            pool0 + WkO + (size_t)hop * 3 * 524288, 524288, nullptr,
            Ebuf, 2097152, 4096, 512, 512,
            qWf + (size_t)hop * 3 * 65536, 65536, nullptr, nullptr, nullptr);
        reduce_u_k<<<dim3(4096, 3), blk, 0, stream>>>(Ebuf, v_att, u, hop * 3);
    }
    utk_k<<<dim3(16, 128), blk, 0, stream>>>(u, kb_mask, out_utk);

    // ---- Part 2: RNN cell MLPs (M = 32768) ----
    const int M = 32768;
    const dim3 g(4, 256, 1);
    mgemm_k<0, 0><<<g, blk, 0, stream>>>(x, hidden, 512, 0, pool0 + w1O[0], 0, arn_b1,
                                         ping, 0, M, 512, 1024, nullptr, 0, nullptr, nullptr, nullptr);
    mgemm_k<0, 1><<<g, blk, 0, stream>>>(ping, nullptr, 512, 0, pool0 + w2O[0], 0, arn_b2,
                                         pong, 0, M, 512, 512, nullptr, 0, nullptr, nullptr, nullptr);
    mgemm_k<1, 1><<<g, blk, 0, stream>>>(pong, nullptr, 512, 0, pool0 + w2O[1], 0, arn_b3,
                                         arnb, 0, M, 512, 512, nullptr, 0, nullptr, nullptr, nullptr);
    mgemm_k<0, 0><<<g, blk, 0, stream>>>(x, hidden, 512, 0, pool0 + w1O[1], 0, add_b1,
                                         ping, 0, M, 512, 1024, nullptr, 0, nullptr, nullptr, nullptr);
    mgemm_k<0, 1><<<g, blk, 0, stream>>>(ping, nullptr, 512, 0, pool0 + w2O[2], 0, add_b2,
                                         pong, 0, M, 512, 512, nullptr, 0, nullptr, nullptr, nullptr);
    mgemm_k<4, 1><<<g, blk, 0, stream>>>(pong, nullptr, 512, 0, pool0 + w2O[3], 0, add_b3,
                                         arnb, 0, M, 512, 512, arnb, 0, nullptr, nullptr, nullptr);
    mgemm_k<0, 0><<<g, blk, 0, stream>>>(x, hidden, 512, 0, pool0 + w1O[2], 0, wc_b1,
                                         ping, 0, M, 512, 1024, nullptr, 0, nullptr, nullptr, nullptr);
    mgemm_k<0, 1><<<g, blk, 0, stream>>>(ping, nullptr, 512, 0, pool0 + w2O[4], 0, wc_b2,
                                         pong, 0, M, 512, 512, nullptr, 0, nullptr, nullptr, nullptr);
    mgemm_k<0, 1><<<g, blk, 0, stream>>>(pong, nullptr, 512, 0, pool0 + w2O[5], 0, wc_b3,
                                         ping, 0, M, 512, 512, nullptr, 0, nullptr, nullptr, nullptr);

    // late wc_w4 conversion into dead pong space (after wc3's pong read)
    ConvTab tL;
    tL.src[0] = wc_w4; tL.dstOff[0] = 0; tL.ksteps[0] = 16; tL.startBlk[0] = 0; tL.nEntries = 1;
    conv_w_k<<<dim3(64), blk, 0, stream>>>(tL, wc4pool);

    eng_k<<<dim3(8192), blk, 0, stream>>>(cell, eng_w, engv);
    mgemm_k<5, 1><<<g, blk, 0, stream>>>(ping, nullptr, 512, 0, wc4pool, 0, wc_b4,
                                         out_cell, 0, M, 512, 512, arnb, 0, cell, engv, out_hid);
}